// Round 1
// 331.371 us; speedup vs baseline: 1.0922x; 1.0922x over previous
//
#include <hip/hip_runtime.h>

// Problem constants (fixed by reference setup_inputs)
#define BATCH 2
#define L_SEQ 768
#define NH 12
#define DH 64
#define ND 8
#define EMB 768
#define RSQRT8 0.35355339059327373f

// ws layout (floats). Total 6,046,480 floats = 24.2 MB
#define OFF_Q    0
#define OFF_K    1179648
#define OFF_V    2359296
#define OFF_L    3538944   // S0 per (bh,d,q): 147456
#define OFF_PART 3686400   // partial stats [bh*8+d][st*4+kq][q]: 2359296
#define OFF_P2   6045696   // per-(b,d,h) stat sums [bd][h][st]: 768
#define OFF_W    6046464   // weights [b][d]: 16

// ---------------------------------------------------------------------------
// K1: fused QKV projection. C = hs @ W + b, scattered to [b][h][l][64] layout.
// 64x64 tiles, 4x4 per thread, fp32 (no fp32 MFMA on CDNA4).
// ---------------------------------------------------------------------------
__global__ __launch_bounds__(256) void k1_qkv(
    const float* __restrict__ hs,
    const float* __restrict__ Wq, const float* __restrict__ bq,
    const float* __restrict__ Wk, const float* __restrict__ bk,
    const float* __restrict__ Wv, const float* __restrict__ bvp,
    float* __restrict__ qw, float* __restrict__ kw, float* __restrict__ vw)
{
    __shared__ float AsT[64][68];
    __shared__ float Bs[64][68];
    const int tid = threadIdx.x;
    const int tx = tid & 15, ty = tid >> 4;
    const int bx = blockIdx.x, by = blockIdx.y, gz = blockIdx.z;
    const float* W    = (gz == 0) ? Wq : (gz == 1 ? Wk : Wv);
    const float* bias = (gz == 0) ? bq : (gz == 1 ? bk : bvp);
    float* dst        = (gz == 0) ? qw : (gz == 1 ? kw : vw);

    const int ldc = tx * 4;

    float acc[4][4];
#pragma unroll
    for (int i = 0; i < 4; i++)
#pragma unroll
        for (int j = 0; j < 4; j++) acc[i][j] = 0.f;

    for (int k0 = 0; k0 < EMB; k0 += 64) {
        __syncthreads();
#pragma unroll
        for (int i = 0; i < 4; i++) {
            int r = ty + 16 * i;
            float4 a = *(const float4*)&hs[(size_t)(by * 64 + r) * EMB + k0 + ldc];
            AsT[ldc + 0][r] = a.x; AsT[ldc + 1][r] = a.y;
            AsT[ldc + 2][r] = a.z; AsT[ldc + 3][r] = a.w;
            *(float4*)&Bs[r][ldc] =
                *(const float4*)&W[(size_t)(k0 + r) * EMB + bx * 64 + ldc];
        }
        __syncthreads();
#pragma unroll 8
        for (int kk = 0; kk < 64; kk++) {
            float av[4], bb[4];
            *(float4*)av = *(const float4*)&AsT[kk][ty * 4];
            *(float4*)bb = *(const float4*)&Bs[kk][tx * 4];
#pragma unroll
            for (int i = 0; i < 4; i++)
#pragma unroll
                for (int j = 0; j < 4; j++)
                    acc[i][j] = fmaf(av[i], bb[j], acc[i][j]);
        }
    }

#pragma unroll
    for (int i = 0; i < 4; i++) {
        int m = by * 64 + ty * 4 + i;
        int b2 = m / L_SEQ, l = m % L_SEQ;
        float o[4];
#pragma unroll
        for (int j = 0; j < 4; j++) o[j] = acc[i][j] + bias[bx * 64 + tx * 4 + j];
        *(float4*)&dst[((size_t)(b2 * NH + bx) * L_SEQ + l) * DH + tx * 4] = *(float4*)o;
    }
}

// ---------------------------------------------------------------------------
// K2: softmax partial stats. Block = (bh, 64-q tile, k-quarter of 192).
// 4 waves x 16 q rows; lane = (qr, d); K chunk [64k][64dim] staged in LDS.
// ---------------------------------------------------------------------------
__global__ __launch_bounds__(256) void k2_stats(
    const float* __restrict__ qw, const float* __restrict__ kw,
    const float* __restrict__ mask, float* __restrict__ part)
{
    __shared__ float k_lds[64 * 64];
    __shared__ float m_lds[64];
    const int tid = threadIdx.x;
    const int lane = tid & 63, w = tid >> 6;
    const int qr = lane >> 3, d = lane & 7;
    const int blk = blockIdx.x;
    const int kq = blk & 3;
    const int t2 = blk >> 2;            // 0..287
    const int bh = t2 / 12;
    const int q0 = (t2 % 12) * 64;
    const int b = bh / NH;
    const int qw0 = q0 + w * 16;

    float qf[2][8];
#pragma unroll
    for (int qq = 0; qq < 2; qq++) {
        const float* qp = &qw[((size_t)bh * L_SEQ + qw0 + qr + qq * 8) * DH + d * 8];
        *(float4*)&qf[qq][0] = *(const float4*)qp;
        *(float4*)&qf[qq][4] = *(const float4*)(qp + 4);
    }
    float S[2] = {0.f, 0.f}, T2[2] = {0.f, 0.f}, SL[2] = {0.f, 0.f};
    float M[2] = {-1e30f, -1e30f};

    const int kb0 = kq * 192;
    for (int c = 0; c < 3; c++) {
        const int kb = kb0 + c * 64;
        __syncthreads();
        {
            const float* src = &kw[((size_t)bh * L_SEQ + kb) * DH];
#pragma unroll
            for (int i = 0; i < 4; i++) {
                int f = tid + 256 * i;
                *(float4*)&k_lds[f * 4] = *(const float4*)&src[f * 4];
            }
            if (tid < 64) m_lds[tid] = mask[b * L_SEQ + kb + tid];
        }
        __syncthreads();
#pragma unroll 4
        for (int kk = 0; kk < 64; kk++) {
            float kv[8];
            *(float4*)&kv[0] = *(const float4*)&k_lds[kk * 64 + d * 8];
            *(float4*)&kv[4] = *(const float4*)&k_lds[kk * 64 + d * 8 + 4];
            float mval = m_lds[kk];
#pragma unroll
            for (int qq = 0; qq < 2; qq++) {
                float s = 0.f;
#pragma unroll
                for (int t = 0; t < 8; t++) s = fmaf(qf[qq][t], kv[t], s);
                s = fmaf(s, RSQRT8, mval);
                float e = __expf(s);
                S[qq] += e;
                T2[qq] = fmaf(e, e, T2[qq]);
                SL[qq] = fmaf(s, e, SL[qq]);
                M[qq] = fmaxf(M[qq], s);
            }
        }
    }
#pragma unroll
    for (int qq = 0; qq < 2; qq++) {
        int q = qw0 + qr + qq * 8;
        size_t base = (size_t)(bh * 8 + d) * 16;
        part[(base + 0 + kq) * 768 + q] = S[qq];
        part[(base + 4 + kq) * 768 + q] = T2[qq];
        part[(base + 8 + kq) * 768 + q] = SL[qq];
        part[(base + 12 + kq) * 768 + q] = M[qq];
    }
}

// ---------------------------------------------------------------------------
// K3a: per-(b,d,h) combine of k-quarters -> row stats -> l_arr + stat sums.
// ---------------------------------------------------------------------------
__global__ __launch_bounds__(256) void k3_reduce(
    const float* __restrict__ part, float* __restrict__ l_arr,
    float* __restrict__ part2)
{
    const int bdh = blockIdx.x;         // ((b*8+d)*12+h)
    const int bd = bdh / 12, h = bdh % 12;
    const int b = bd >> 3, d = bd & 7;
    const int bh = b * NH + h;
    const int tid = threadIdx.x;
    const int lane = tid & 63, wave = tid >> 6;
    const size_t base = (size_t)(bh * 8 + d) * 16;
    float acc[4] = {0.f, 0.f, 0.f, 0.f};

    for (int q = tid; q < 768; q += 256) {
        float Sv = 0.f, T2v = 0.f, SLv = 0.f, Mv = -1e30f;
#pragma unroll
        for (int kq = 0; kq < 4; kq++) {
            Sv  += part[(base + 0 + kq) * 768 + q];
            T2v += part[(base + 4 + kq) * 768 + q];
            SLv += part[(base + 8 + kq) * 768 + q];
            Mv = fmaxf(Mv, part[(base + 12 + kq) * 768 + q]);
        }
        l_arr[(size_t)(bh * 8 + d) * 768 + q] = Sv;
        float inv = 1.0f / Sv;
        float hhi = T2v * inv * inv;
        float maxp = __expf(Mv) * inv;
        float ent = __logf(Sv) - SLv * inv;
        float var = (hhi - (1.0f / 768.0f)) * (1.0f / 767.0f);
        acc[0] += var; acc[1] += maxp; acc[2] += ent; acc[3] += hhi;
    }
    __shared__ float red[4][4];
#pragma unroll
    for (int st = 0; st < 4; st++) {
        float a = acc[st];
#pragma unroll
        for (int off = 32; off > 0; off >>= 1) a += __shfl_xor(a, off, 64);
        acc[st] = a;
    }
    if (lane == 0) {
#pragma unroll
        for (int st = 0; st < 4; st++) red[wave][st] = acc[st];
    }
    __syncthreads();
    if (tid == 0) {
#pragma unroll
        for (int st = 0; st < 4; st++)
            part2[(size_t)(bd * 12 + h) * 4 + st] =
                red[0][st] + red[1][st] + red[2][st] + red[3][st];
    }
}

// ---------------------------------------------------------------------------
// K3b: sum over h, min-max norm over d, softmax(2.5*score) -> weights[b][d].
// ---------------------------------------------------------------------------
__global__ __launch_bounds__(64) void k3_weights(
    const float* __restrict__ part2, float* __restrict__ wgt)
{
    __shared__ float stats_l[64];       // [b][d][st]
    const int tid = threadIdx.x;
    {
        const int bd = tid >> 2, st = tid & 3;
        float s = 0.f;
#pragma unroll
        for (int h = 0; h < 12; h++) s += part2[(size_t)(bd * 12 + h) * 4 + st];
        stats_l[tid] = s * (1.0f / 9216.0f);
    }
    __syncthreads();
    if (tid == 0) {
        for (int b = 0; b < BATCH; b++) {
            float v[4][8];
            for (int st = 0; st < 4; st++)
                for (int d = 0; d < 8; d++) v[st][d] = stats_l[(b * 8 + d) * 4 + st];
            float nrm[4][8];
            for (int st = 0; st < 4; st++) {
                float mn = v[st][0], mx = v[st][0];
                for (int d = 1; d < 8; d++) { mn = fminf(mn, v[st][d]); mx = fmaxf(mx, v[st][d]); }
                float rng = fmaxf(mx - mn, 1e-12f);
                for (int d = 0; d < 8; d++) nrm[st][d] = (v[st][d] - mn) / rng;
            }
            float sc[8];
            for (int d = 0; d < 8; d++)
                sc[d] = 0.5f * nrm[0][d] + 0.3f * nrm[1][d] + 0.2f * nrm[3][d] - 0.4f * nrm[2][d];
            float m = 2.5f * sc[0];
            for (int d = 1; d < 8; d++) m = fmaxf(m, 2.5f * sc[d]);
            float e8[8]; float ssum = 0.f;
            for (int d = 0; d < 8; d++) { e8[d] = __expf(2.5f * sc[d] - m); ssum += e8[d]; }
            for (int d = 0; d < 8; d++) wgt[b * ND + d] = e8[d] / ssum;
        }
    }
}

// ---------------------------------------------------------------------------
// K45 (round-8 fusion): a4 + ctx in ONE kernel, depth reduction LANE-SERIAL.
// ROUND-7 LESSON (rocprof): old k4 was DS-pipe bound, not VALU bound
// (VALUBusy 40%, MfmaUtil 0, HBM 8%): 3 __shfl_xor (ds_bpermute) per a4
// value in a dependent chain = 384 DS shuffles per wave per 64k, which
// 2.25 waves/SIMD cannot hide. And k5 existed only to re-read the 56.6 MB
// a4 tensor from HBM.
// FIX: each lane holds its FULL 64-float q row in VGPRs and computes the
// whole a4(q,k) = sum_d c0[d]*exp(s_d) alone: 64 FMA + 8 exp, ZERO
// cross-lane ops. a4 tile goes through a per-wave LDS buffer (same-wave
// lgkmcnt dep, no barrier) for (a) coalesced global store, (b) fused
// ctx += a4 @ V accumulation in registers. k-ascending FMA order kept
// bitwise-identical to old k4/k5.
// Block = (bh, 32-q tile), grid 576, 4 waves x 8 q rows.
// LDS: K [64][68] (pad 68: phase-A read granule = (kc + 4t) mod 8,
// conflict-free with k = kc + 8*j lane mapping) + V [64][64] + a4 [4][8][68].
// Total 42.75 KB -> 3 blocks/CU.
// ---------------------------------------------------------------------------
__global__ __launch_bounds__(256) void k45_fused(
    const float* __restrict__ qw, const float* __restrict__ kw,
    const float* __restrict__ vw, const float* __restrict__ mask,
    const float* __restrict__ l_arr, const float* __restrict__ wgt,
    float* __restrict__ out_a4, float* __restrict__ out_ctx)
{
    __shared__ float k_lds[64 * 68];        // [k][dh] pad 68
    __shared__ float v_lds[64 * 64];        // [k][dh] natural
    __shared__ float a4_lds[4][8 * 68];     // per-wave [qr][k] pad 68
    __shared__ float m_lds[64];

    const int tid = threadIdx.x;
    const int lane = tid & 63, w = tid >> 6;
    const int blk = blockIdx.x;
    const int bh = blk / 24;                // 0..23
    const int q0 = (blk % 24) * 32;
    const int b = bh / NH, h = bh % NH;
    const int qw0 = q0 + w * 8;             // wave owns rows qw0..qw0+7

    // phase A lane mapping: one q row, 8 k's (k = kc + 8j)
    const int qr = lane >> 3;               // 0..7
    const int kc = lane & 7;                // 0..7
    // phase B lane mapping: rows (rb, rb+4), dh cols cb*4..cb*4+3
    const int rb = lane >> 4;               // 0..3
    const int cb = lane & 15;               // 0..15

    // q row (64 floats) in VGPRs; 8 lanes per qr hold redundant copies.
    float qf[64];
    {
        const float* qp = &qw[((size_t)bh * L_SEQ + qw0 + qr) * DH];
#pragma unroll
        for (int t = 0; t < 16; t++)
            *(float4*)&qf[t * 4] = *(const float4*)&qp[t * 4];
    }
    // c0[d] = w_d / l(bh,d,row): same normalization as old k4.
    float c0[8];
#pragma unroll
    for (int d = 0; d < 8; d++)
        c0[d] = wgt[b * ND + d] / l_arr[(size_t)(bh * 8 + d) * L_SEQ + qw0 + qr];

    float4 acc0 = {0.f, 0.f, 0.f, 0.f};
    float4 acc1 = {0.f, 0.f, 0.f, 0.f};

    for (int c = 0; c < 12; c++) {
        const int kb = c * 64;
        __syncthreads();
        {   // stage K chunk [64][64] -> padded [64][68], V chunk straight.
            const float* ksrc = &kw[((size_t)bh * L_SEQ + kb) * DH];
            const float* vsrc = &vw[((size_t)bh * L_SEQ + kb) * DH];
#pragma unroll
            for (int i = 0; i < 4; i++) {
                int f = tid + 256 * i;                  // 0..1023
                int row = f >> 4, col = (f & 15) * 4;
                *(float4*)&k_lds[row * 68 + col] = *(const float4*)&ksrc[f * 4];
                *(float4*)&v_lds[f * 4] = *(const float4*)&vsrc[f * 4];
            }
            if (tid < 64) m_lds[tid] = mask[b * L_SEQ + kb + tid];
        }
        __syncthreads();

        // ---- Phase A: a4 tile [8q][64k], fully in-lane (no shuffles) ----
#pragma unroll 2
        for (int j = 0; j < 8; j++) {
            const int k = kc + 8 * j;
            const float* krow = &k_lds[k * 68];
            const float mval = m_lds[k];
            float a4 = 0.f;
#pragma unroll
            for (int d = 0; d < 8; d++) {
                float kv[8];
                *(float4*)&kv[0] = *(const float4*)&krow[d * 8];
                *(float4*)&kv[4] = *(const float4*)&krow[d * 8 + 4];
                float s = 0.f;
#pragma unroll
                for (int t = 0; t < 8; t++) s = fmaf(qf[d * 8 + t], kv[t], s);
                s = fmaf(s, RSQRT8, mval);
                a4 = fmaf(c0[d], __expf(s), a4);
            }
            a4_lds[w][qr * 68 + k] = a4;
        }

        // ---- a4 global store (coalesced; same-wave LDS dep -> lgkmcnt) ----
        {
            const int r = lane >> 3, c8 = (lane & 7) * 8;
            float* dst = &out_a4[((size_t)bh * L_SEQ + qw0 + r) * L_SEQ + kb + c8];
            *(float4*)&dst[0] = *(const float4*)&a4_lds[w][r * 68 + c8];
            *(float4*)&dst[4] = *(const float4*)&a4_lds[w][r * 68 + c8 + 4];
        }

        // ---- Phase B: ctx += a4_tile @ V_chunk (k ascending, as old k5) ----
#pragma unroll 4
        for (int kg = 0; kg < 16; kg++) {
            float a0[4], a1[4];
            *(float4*)a0 = *(const float4*)&a4_lds[w][rb * 68 + kg * 4];
            *(float4*)a1 = *(const float4*)&a4_lds[w][(rb + 4) * 68 + kg * 4];
#pragma unroll
            for (int u = 0; u < 4; u++) {
                float4 vv = *(const float4*)&v_lds[(kg * 4 + u) * 64 + cb * 4];
                acc0.x = fmaf(a0[u], vv.x, acc0.x);
                acc0.y = fmaf(a0[u], vv.y, acc0.y);
                acc0.z = fmaf(a0[u], vv.z, acc0.z);
                acc0.w = fmaf(a0[u], vv.w, acc0.w);
                acc1.x = fmaf(a1[u], vv.x, acc1.x);
                acc1.y = fmaf(a1[u], vv.y, acc1.y);
                acc1.z = fmaf(a1[u], vv.z, acc1.z);
                acc1.w = fmaf(a1[u], vv.w, acc1.w);
            }
        }
    }

    // ---- ctx store: rows (qw0+rb, qw0+rb+4), dh cols cb*4..+3 ----
    {
        const int row0 = qw0 + rb, row1 = qw0 + rb + 4;
        *(float4*)&out_ctx[((size_t)b * L_SEQ + row0) * EMB + h * DH + cb * 4] = acc0;
        *(float4*)&out_ctx[((size_t)b * L_SEQ + row1) * EMB + h * DH + cb * 4] = acc1;
    }
}

// ---------------------------------------------------------------------------
extern "C" void kernel_launch(void* const* d_in, const int* in_sizes, int n_in,
                              void* d_out, int out_size, void* d_ws, size_t ws_size,
                              hipStream_t stream)
{
    const float* hs   = (const float*)d_in[0];
    const float* mask = (const float*)d_in[1];
    const float* Wq   = (const float*)d_in[2];
    const float* bq   = (const float*)d_in[3];
    const float* Wk   = (const float*)d_in[4];
    const float* bk   = (const float*)d_in[5];
    const float* Wv   = (const float*)d_in[6];
    const float* bv   = (const float*)d_in[7];

    float* ws = (float*)d_ws;
    float* qw = ws + OFF_Q;
    float* kw = ws + OFF_K;
    float* vw = ws + OFF_V;
    float* l_arr = ws + OFF_L;
    float* part  = ws + OFF_PART;
    float* part2 = ws + OFF_P2;
    float* wgt   = ws + OFF_W;

    float* out_ctx = (float*)d_out;                                  // [B, L, 768]
    float* out_a4  = (float*)d_out + (size_t)BATCH * L_SEQ * EMB;    // [B, H, L, L]

    k1_qkv<<<dim3(12, 24, 3), 256, 0, stream>>>(hs, Wq, bq, Wk, bk, Wv, bv, qw, kw, vw);
    k2_stats<<<dim3(1152), 256, 0, stream>>>(qw, kw, mask, part);
    k3_reduce<<<dim3(192), 256, 0, stream>>>(part, l_arr, part2);
    k3_weights<<<dim3(1), 64, 0, stream>>>(part2, wgt);
    k45_fused<<<dim3(576), 256, 0, stream>>>(qw, kw, vw, mask, l_arr, wgt, out_a4, out_ctx);
}